// Round 1
// baseline (15994.408 us; speedup 1.0000x reference)
//
#include <hip/hip_runtime.h>
#include <math.h>

// ---------------------------------------------------------------------------
// TransformerDecoder: incremental KV-cache decode, 64 sequential steps.
// B=8, S_SRC=256, T=64, D=256, H=8, HD=32, DFF=1024, NC=128, L=2.
// All fp32. Latency-bound: ~14 small kernels per step, LN fused into consumers.
// ---------------------------------------------------------------------------

#define B_   8
#define SSRC 256
#define T_   64
#define D_   256
#define H_   8
#define HD_  32
#define DFF_ 1024
#define NC_  128
#define L_   2
#define EPS_ 1e-5f
#define SCALE_ 0.17677669529663687f  // 1/sqrt(32)

#define DEV __device__ __forceinline__

DEV float wsum(float v) {
#pragma unroll
  for (int o = 32; o; o >>= 1) v += __shfl_xor(v, o, 64);
  return v;
}
DEV float wmax(float v) {
#pragma unroll
  for (int o = 32; o; o >>= 1) v = fmaxf(v, __shfl_xor(v, o, 64));
  return v;
}

// dot of a 256-float LDS row with a 256-float global row (float4 vectorized)
DEV float dot256(const float* a, const float* __restrict__ w) {
  const float4* a4 = (const float4*)a;
  const float4* w4 = (const float4*)w;
  float acc = 0.f;
#pragma unroll 16
  for (int i = 0; i < 64; ++i) {
    float4 av = a4[i], wv = w4[i];
    acc += av.x * wv.x + av.y * wv.y + av.z * wv.z + av.w * wv.w;
  }
  return acc;
}

// In-place LayerNorm of a single 256-float LDS row; 256 threads. red = LDS[8].
DEV void ln_row(float* xs, const float* __restrict__ g, const float* __restrict__ bb, float* red) {
  int tid = threadIdx.x, wid = tid >> 6, lane = tid & 63;
  float v = xs[tid];
  float s = wsum(v), s2 = wsum(v * v);
  if (lane == 0) { red[wid] = s; red[4 + wid] = s2; }
  __syncthreads();
  float S = red[0] + red[1] + red[2] + red[3];
  float S2 = red[4] + red[5] + red[6] + red[7];
  float m = S * (1.f / 256.f);
  float rs = rsqrtf(S2 * (1.f / 256.f) - m * m + EPS_);
  __syncthreads();
  xs[tid] = (v - m) * rs * g[tid] + bb[tid];
  __syncthreads();
}

// In-place LayerNorm of 8 rows x 256 in LDS; 256 threads (4 waves, 2 rows each).
DEV void ln_rows8(float (*x8)[256], const float* __restrict__ g, const float* __restrict__ bb, float* mv) {
  int tid = threadIdx.x, wid = tid >> 6, lane = tid & 63;
  for (int r = wid; r < 8; r += 4) {
    float s = 0.f, s2 = 0.f;
    for (int i = lane; i < 256; i += 64) { float v = x8[r][i]; s += v; s2 += v * v; }
    s = wsum(s); s2 = wsum(s2);
    if (lane == 0) {
      float m = s * (1.f / 256.f);
      mv[r] = m;
      mv[8 + r] = rsqrtf(s2 * (1.f / 256.f) - m * m + EPS_);
    }
  }
  __syncthreads();
  for (int i = tid; i < 2048; i += 256) {
    int r = i >> 8, c = i & 255;
    x8[r][c] = (x8[r][c] - mv[r]) * mv[8 + r] * g[c] + bb[c];
  }
  __syncthreads();
}

// ---------------- prologue kernels ----------------

__global__ void k_pe(float* __restrict__ pe) {
  int idx = blockIdx.x * 256 + threadIdx.x;  // grid 64 -> 16384
  int t = idx >> 8, d = idx & 255;
  int i = d >> 1;
  float div = expf((float)(2 * i) * (-9.210340371976184f / 256.f));  // ln(10000)
  float a = (float)t * div;
  pe[idx] = (d & 1) ? cosf(a) : sinf(a);
}

// cross-attn K/V precompute: mem_kv[l,b,s,e] = enc[b,s,:] . ca_wqkv[l,256+e,:] + bias
// grid 256: (l, b, s-block of 16); 256 threads (one e column per thread, x2 halves)
__global__ void k_memkv(const float* __restrict__ enc, const float* __restrict__ wqkv,
                        const float* __restrict__ bqkv, float* __restrict__ mk,
                        float* __restrict__ mv_) {
  __shared__ __align__(16) float e8[16][256];
  int blk = blockIdx.x, tid = threadIdx.x;
  int l = blk >> 7, b = (blk >> 4) & 7, s0 = (blk & 15) * 16;
  const float* W = wqkv + (size_t)l * 768 * 256;
  const float* bb = bqkv + l * 768;
  for (int i = tid; i < 4096; i += 256)
    e8[i >> 8][i & 255] = enc[(size_t)(b * 256 + s0 + (i >> 8)) * 256 + (i & 255)];
  __syncthreads();
  for (int half = 0; half < 2; ++half) {
    const float4* wr = (const float4*)(W + (size_t)(256 + half * 256 + tid) * 256);
    float acc[16];
#pragma unroll
    for (int s = 0; s < 16; ++s) acc[s] = 0.f;
    for (int i = 0; i < 64; ++i) {
      float4 w = wr[i];
#pragma unroll
      for (int s = 0; s < 16; ++s) {
        float4 a = ((const float4*)e8[s])[i];
        acc[s] += a.x * w.x + a.y * w.y + a.z * w.z + a.w * w.w;
      }
    }
    float bias = bb[256 + half * 256 + tid];
    float* dst = half ? mv_ : mk;
    int h = tid >> 5, hd = tid & 31;
    for (int s = 0; s < 16; ++s)
      dst[(size_t)(((l * 8 + b) * 8 + h) * 256 + (s0 + s)) * 32 + hd] = acc[s] + bias;
  }
}

__global__ void k_emb0(const float* __restrict__ embb, const float* __restrict__ pe,
                       float* __restrict__ x0) {
  int b = blockIdx.x, tid = threadIdx.x;
  x0[b * 256 + tid] = embb[tid] + pe[tid];  // buf row is zeros at t=0
}

// ---------------- per-step kernels ----------------

// self-attn: qkv for current token + KV-cache append + causal attention.
// grid 64 = (b,h); optional LN of input row (layer-1 input = LN3(r3_l0)).
__global__ void k_sa(const float* __restrict__ xin, const float* __restrict__ lng,
                     const float* __restrict__ lnb, const float* __restrict__ W,
                     const float* __restrict__ bq, float* __restrict__ kc,
                     float* __restrict__ vc, int t, float* __restrict__ obuf) {
  __shared__ __align__(16) float xs[256];
  __shared__ float red[8];
  __shared__ __align__(16) float qv[32], kt[32], vt[32];
  __shared__ float sc[64];
  __shared__ float part[8][32];
  int b = blockIdx.x >> 3, h = blockIdx.x & 7, tid = threadIdx.x;
  xs[tid] = xin[b * 256 + tid];
  __syncthreads();
  if (lng) ln_row(xs, lng, lnb, red);
  if (tid < 96) {
    int which = tid >> 5, j = tid & 31;
    int row = which * 256 + h * 32 + j;
    float acc = dot256(xs, W + (size_t)row * 256) + bq[row];
    if (which == 0) qv[j] = acc;
    else if (which == 1) { kt[j] = acc; kc[((b * 8 + h) * 64 + t) * 32 + j] = acc; }
    else { vt[j] = acc; vc[((b * 8 + h) * 64 + t) * 32 + j] = acc; }
  }
  __syncthreads();
  if (tid < 64) {
    float s = -3.0e38f;
    if (tid <= t) {
      const float* kr = (tid == t) ? kt : (kc + ((b * 8 + h) * 64 + tid) * 32);
      float a = 0.f;
#pragma unroll
      for (int i = 0; i < 32; ++i) a += qv[i] * kr[i];
      s = a * SCALE_;
    }
    float mx = wmax(s);
    float e = (tid <= t) ? expf(s - mx) : 0.f;
    float sm = wsum(e);
    sc[tid] = e / sm;
  }
  __syncthreads();
  int g = tid >> 5, lane = tid & 31;
  float a = 0.f;
  int k0 = g * 8, k1 = min(k0 + 8, t + 1);
  for (int k = k0; k < k1; ++k) {
    const float* vr = (k == t) ? vt : (vc + ((b * 8 + h) * 64 + k) * 32);
    a += sc[k] * vr[lane];
  }
  part[g][lane] = a;
  __syncthreads();
  if (tid < 32) {
    float o = 0.f;
#pragma unroll
    for (int gg = 0; gg < 8; ++gg) o += part[gg][tid];
    obuf[b * 256 + h * 32 + tid] = o;
  }
}

// cross-attn: qc = LN1(r1) @ Wq.T + b; softmax over 256 memory positions; PV.
// grid 64 = (b,h)
__global__ void k_ca(const float* __restrict__ r1, const float* __restrict__ g1,
                     const float* __restrict__ b1, const float* __restrict__ wq,
                     const float* __restrict__ bq, const float* __restrict__ mk,
                     const float* __restrict__ mv_, float* __restrict__ obuf) {
  __shared__ __align__(16) float xs[256];
  __shared__ float red[8];
  __shared__ __align__(16) float qc[32];
  __shared__ float ps[256];
  __shared__ float part[8][32];
  int b = blockIdx.x >> 3, h = blockIdx.x & 7, tid = threadIdx.x;
  xs[tid] = r1[b * 256 + tid];
  __syncthreads();
  ln_row(xs, g1, b1, red);
  if (tid < 32) {
    int row = h * 32 + tid;
    qc[tid] = dot256(xs, wq + (size_t)row * 256) + bq[row];
  }
  __syncthreads();
  const float* kb = mk + (size_t)(b * 8 + h) * 256 * 32;
  float a = 0.f;
  {
    const float4* kr = (const float4*)(kb + tid * 32);
    const float4* qr = (const float4*)qc;
#pragma unroll
    for (int i = 0; i < 8; ++i) {
      float4 k4 = kr[i], q4 = qr[i];
      a += k4.x * q4.x + k4.y * q4.y + k4.z * q4.z + k4.w * q4.w;
    }
  }
  float s = a * SCALE_;
  int wid = tid >> 6, lane = tid & 63;
  float mx = wmax(s);
  if (lane == 0) red[wid] = mx;
  __syncthreads();
  mx = fmaxf(fmaxf(red[0], red[1]), fmaxf(red[2], red[3]));
  float e = expf(s - mx);
  float sm = wsum(e);
  if (lane == 0) red[4 + wid] = sm;
  __syncthreads();
  sm = red[4] + red[5] + red[6] + red[7];
  ps[tid] = e / sm;
  __syncthreads();
  int g = tid >> 5, lane2 = tid & 31;
  const float* vb = mv_ + (size_t)(b * 8 + h) * 256 * 32;
  float acc = 0.f;
  for (int s2 = g * 32; s2 < g * 32 + 32; ++s2) acc += ps[s2] * vb[s2 * 32 + lane2];
  part[g][lane2] = acc;
  __syncthreads();
  if (tid < 32) {
    float o = 0.f;
#pragma unroll
    for (int gg = 0; gg < 8; ++gg) o += part[gg][tid];
    obuf[b * 256 + h * 32 + tid] = o;
  }
}

// generic K=256 matmul over all 8 batch rows: out = [LN?](in) @ W.T + bias
//                                                   (+ [LN?](resid)) (+relu)
// grid = ncols/64 blocks; 256 threads.
__global__ void k_mm256(const float* __restrict__ in, const float* __restrict__ ilng,
                        const float* __restrict__ ilnb, const float* __restrict__ W,
                        const float* __restrict__ bias, const float* __restrict__ resid,
                        const float* __restrict__ rlng, const float* __restrict__ rlnb,
                        float* __restrict__ out, int relu) {
  __shared__ __align__(16) float in8[8][256];
  __shared__ __align__(16) float re8[8][256];
  __shared__ float mv[16];
  int tid = threadIdx.x;
  for (int i = tid; i < 2048; i += 256) in8[i >> 8][i & 255] = in[i];
  if (resid)
    for (int i = tid; i < 2048; i += 256) re8[i >> 8][i & 255] = resid[i];
  __syncthreads();
  if (ilng) ln_rows8(in8, ilng, ilnb, mv);
  if (resid && rlng) ln_rows8(re8, rlng, rlnb, mv);
  int c0 = blockIdx.x * 64;
  int ncols = gridDim.x * 64;
  for (int pair = tid; pair < 512; pair += 256) {
    int bb = pair >> 6, c = c0 + (pair & 63);
    float acc = dot256(in8[bb], W + (size_t)c * 256) + bias[c];
    if (resid) acc += re8[bb][c];
    if (relu) acc = fmaxf(acc, 0.f);
    out[bb * ncols + c] = acc;
  }
}

// ffn second matmul (K=1024): r3 = LN2(r2) + h @ w2.T + b2.  grid 8 x 32 cols.
__global__ void k_f2(const float* __restrict__ hbuf, const float* __restrict__ r2,
                     const float* __restrict__ g2, const float* __restrict__ b2g,
                     const float* __restrict__ W, const float* __restrict__ bias,
                     float* __restrict__ out) {
  __shared__ __align__(16) float h8[8][1024];
  __shared__ __align__(16) float x8[8][256];
  __shared__ float mv[16];
  int tid = threadIdx.x;
  for (int i = tid; i < 8192; i += 256) h8[i >> 10][i & 1023] = hbuf[i];
  for (int i = tid; i < 2048; i += 256) x8[i >> 8][i & 255] = r2[i];
  __syncthreads();
  ln_rows8(x8, g2, b2g, mv);
  int c = blockIdx.x * 32 + (tid & 31);
  int bb = tid >> 5;
  const float4* hv = (const float4*)h8[bb];
  const float4* wv = (const float4*)(W + (size_t)c * 1024);
  float acc = 0.f;
#pragma unroll 8
  for (int i = 0; i < 256; ++i) {
    float4 a4 = hv[i], w4 = wv[i];
    acc += a4.x * w4.x + a4.y * w4.y + a4.z * w4.z + a4.w * w4.w;
  }
  out[bb * 256 + c] = acc + bias[c] + x8[bb][c];
}

// head stage 2: bn-affine+relu, logits, write output, embed next-step input.
// grid 8 (per b).
__global__ void k_head2(const float* __restrict__ ybuf, const float* __restrict__ bng,
                        const float* __restrict__ bnb, const float* __restrict__ w2,
                        const float* __restrict__ b2, const float* __restrict__ embw,
                        const float* __restrict__ embb, const float* __restrict__ pe,
                        float* __restrict__ out, float* __restrict__ x0, int t) {
  __shared__ __align__(16) float y2[256];
  __shared__ __align__(16) float lg[128];
  int b = blockIdx.x, tid = threadIdx.x;
  float bnscale = 1.0f / sqrtf(1.0f + 1e-5f);
  y2[tid] = fmaxf(ybuf[b * 256 + tid] * bnscale * bng[tid] + bnb[tid], 0.f);
  __syncthreads();
  if (tid < 128) {
    float v = dot256(y2, w2 + (size_t)tid * 256) + b2[tid];
    lg[tid] = v;
    out[(b * 64 + t) * 128 + tid] = v;
  }
  __syncthreads();
  if (t < 63) {
    float acc = embb[tid];
    const float4* er = (const float4*)(embw + (size_t)tid * 128);
    const float4* lr = (const float4*)lg;
#pragma unroll 8
    for (int i = 0; i < 32; ++i) {
      float4 e = er[i], l = lr[i];
      acc += e.x * l.x + e.y * l.y + e.z * l.z + e.w * l.w;
    }
    x0[b * 256 + tid] = acc + pe[(t + 1) * 256 + tid];
  }
}

// ---------------------------------------------------------------------------

extern "C" void kernel_launch(void* const* d_in, const int* in_sizes, int n_in,
                              void* d_out, int out_size, void* d_ws, size_t ws_size,
                              hipStream_t stream) {
  (void)in_sizes; (void)n_in; (void)out_size; (void)ws_size;
  const float* enc     = (const float*)d_in[0];
  const float* emb_w   = (const float*)d_in[1];
  const float* emb_b   = (const float*)d_in[2];
  const float* sa_wqkv = (const float*)d_in[3];
  const float* sa_bqkv = (const float*)d_in[4];
  const float* sa_wo   = (const float*)d_in[5];
  const float* sa_bo   = (const float*)d_in[6];
  const float* ca_wqkv = (const float*)d_in[7];
  const float* ca_bqkv = (const float*)d_in[8];
  const float* ca_wo   = (const float*)d_in[9];
  const float* ca_bo   = (const float*)d_in[10];
  const float* ln1_g   = (const float*)d_in[11];
  const float* ln1_b   = (const float*)d_in[12];
  const float* ln2_g   = (const float*)d_in[13];
  const float* ln2_b   = (const float*)d_in[14];
  const float* ffn_w1  = (const float*)d_in[15];
  const float* ffn_b1  = (const float*)d_in[16];
  const float* ffn_w2  = (const float*)d_in[17];
  const float* ffn_b2  = (const float*)d_in[18];
  const float* ln3_g   = (const float*)d_in[19];
  const float* ln3_b   = (const float*)d_in[20];
  const float* op_w1   = (const float*)d_in[21];
  const float* op_b1   = (const float*)d_in[22];
  const float* bn_g    = (const float*)d_in[23];
  const float* bn_b    = (const float*)d_in[24];
  const float* op_w2   = (const float*)d_in[25];
  const float* op_b2   = (const float*)d_in[26];

  float* out = (float*)d_out;
  float* ws  = (float*)d_ws;

  // workspace layout (floats)
  const size_t NPE = 64 * 256;                  // 16384
  const size_t NMK = (size_t)L_ * 8 * 8 * 256 * 32;  // 1048576
  const size_t NKC = (size_t)L_ * 8 * 8 * 64 * 32;   // 262144
  float* pe   = ws;
  float* mk   = pe + NPE;
  float* mv   = mk + NMK;
  float* kc   = mv + NMK;
  float* vc   = kc + NKC;
  float* x0   = vc + NKC;                 // [8][256]
  float* r1   = x0 + 2048;                // [L][8][256]
  float* r2   = r1 + 2 * 2048;
  float* r3   = r2 + 2 * 2048;
  float* obuf = r3 + 2 * 2048;            // [8][256]
  float* hbuf = obuf + 2048;              // [8][1024]
  float* ybuf = hbuf + 8192;              // [8][256]

  const size_t MK_L = (size_t)8 * 8 * 256 * 32;  // per-layer mem_k/v stride
  const size_t KC_L = (size_t)8 * 8 * 64 * 32;   // per-layer cache stride

  k_pe<<<64, 256, 0, stream>>>(pe);
  k_memkv<<<256, 256, 0, stream>>>(enc, ca_wqkv, ca_bqkv, mk, mv);
  k_emb0<<<8, 256, 0, stream>>>(emb_b, pe, x0);

  for (int t = 0; t < 64; ++t) {
    for (int l = 0; l < 2; ++l) {
      const float* xi  = (l == 0) ? x0 : (r3 + 0 * 2048);
      const float* xig = (l == 0) ? nullptr : (ln3_g + 0 * 256);
      const float* xib = (l == 0) ? nullptr : (ln3_b + 0 * 256);
      // self-attn (qkv + cache + attention)
      k_sa<<<64, 256, 0, stream>>>(xi, xig, xib,
                                   sa_wqkv + (size_t)l * 768 * 256, sa_bqkv + l * 768,
                                   kc + l * KC_L, vc + l * KC_L, t, obuf);
      // r1 = x + o @ wo.T + bo     (x = LN3(prev layer out) for l=1)
      k_mm256<<<4, 256, 0, stream>>>(obuf, nullptr, nullptr,
                                     sa_wo + (size_t)l * 65536, sa_bo + l * 256,
                                     xi, xig, xib, r1 + l * 2048, 0);
      // cross-attn
      k_ca<<<64, 256, 0, stream>>>(r1 + l * 2048, ln1_g + l * 256, ln1_b + l * 256,
                                   ca_wqkv + (size_t)l * 768 * 256, ca_bqkv + l * 768,
                                   mk + l * MK_L, mv + l * MK_L, obuf);
      // r2 = LN1(r1) + oc @ wo.T + bo
      k_mm256<<<4, 256, 0, stream>>>(obuf, nullptr, nullptr,
                                     ca_wo + (size_t)l * 65536, ca_bo + l * 256,
                                     r1 + l * 2048, ln1_g + l * 256, ln1_b + l * 256,
                                     r2 + l * 2048, 0);
      // h = relu(LN2(r2) @ w1.T + b1)
      k_mm256<<<16, 256, 0, stream>>>(r2 + l * 2048, ln2_g + l * 256, ln2_b + l * 256,
                                      ffn_w1 + (size_t)l * 1024 * 256, ffn_b1 + l * 1024,
                                      nullptr, nullptr, nullptr, hbuf, 1);
      // r3 = LN2(r2) + h @ w2.T + b2
      k_f2<<<8, 256, 0, stream>>>(hbuf, r2 + l * 2048, ln2_g + l * 256, ln2_b + l * 256,
                                  ffn_w2 + (size_t)l * 256 * 1024, ffn_b2 + l * 256,
                                  r3 + l * 2048);
    }
    // y1 = LN3(r3_l1) @ op_w1.T + op_b1
    k_mm256<<<4, 256, 0, stream>>>(r3 + 2048, ln3_g + 256, ln3_b + 256,
                                   op_w1, op_b1, nullptr, nullptr, nullptr, ybuf, 0);
    // logits + write output row t + embed next-step input
    k_head2<<<8, 256, 0, stream>>>(ybuf, bn_g, bn_b, op_w2, op_b2,
                                   emb_w, emb_b, pe, out, x0, t);
  }
}

// Round 2
// 8738.217 us; speedup vs baseline: 1.8304x; 1.8304x over previous
//
#include <hip/hip_runtime.h>
#include <math.h>

// ---------------------------------------------------------------------------
// TransformerDecoder: persistent-kernel incremental KV-cache decode.
// B=8, S_SRC=256, T=64, D=256, H=8, HD=32, DFF=1024, NC=128, L=2. fp32.
// 64 blocks x 256 threads co-resident; custom inter-block barrier; all
// cross-block activations via agent-scope relaxed atomics (bypass L1/L2 so no
// cache flushes needed -> weights stay hot in per-XCD L2 across all steps).
// ---------------------------------------------------------------------------

#define NBLK 64
#define EPS_ 1e-5f
#define SCALE_ 0.17677669529663687f   // 1/sqrt(32)
#define BNS 0.99999500003749969f      // 1/sqrt(1+1e-5)

#define DEV __device__ __forceinline__

DEV float ald(const float* p) {
  return __hip_atomic_load(p, __ATOMIC_RELAXED, __HIP_MEMORY_SCOPE_AGENT);
}
DEV void ast(float* p, float v) {
  __hip_atomic_store(p, v, __ATOMIC_RELAXED, __HIP_MEMORY_SCOPE_AGENT);
}
DEV int aldi(const int* p) {
  return __hip_atomic_load(p, __ATOMIC_RELAXED, __HIP_MEMORY_SCOPE_AGENT);
}
DEV void asti(int* p, int v) {
  __hip_atomic_store(p, v, __ATOMIC_RELAXED, __HIP_MEMORY_SCOPE_AGENT);
}

DEV float wsum(float v) {
#pragma unroll
  for (int o = 32; o; o >>= 1) v += __shfl_xor(v, o, 64);
  return v;
}
DEV float wmax(float v) {
#pragma unroll
  for (int o = 32; o; o >>= 1) v = fmaxf(v, __shfl_xor(v, o, 64));
  return v;
}

// grid barrier: bar[1..63] per-block arrival counters, bar[64] generation.
// All data exchange goes through agent-scope atomics, so no cache-flush fence
// is needed in the main loop (fence=true only after the prologue, to publish
// the normal-store pe/mk/mv tables).
DEV void gbar(int* bar, int blk, int tid, int& mybar, bool fence) {
  __syncthreads();
  ++mybar;
  if (blk == 0) {
    if (fence && tid == 0) __threadfence();
    if (tid > 0 && tid < 64) {
      while (aldi(&bar[tid]) < mybar) {}
    }
    __syncthreads();
    if (tid == 0) asti(&bar[64], mybar);
    asm volatile("" ::: "memory");
  } else {
    if (tid == 0) {
      if (fence) __threadfence();
      asti(&bar[blk], mybar);
      while (aldi(&bar[64]) < mybar) {}
    }
    asm volatile("" ::: "memory");
  }
  __syncthreads();
}

// dot of 256-float LDS row with 256-float global row
DEV float dot256(const float* a, const float* __restrict__ w) {
  const float4* a4 = (const float4*)a;
  const float4* w4 = (const float4*)w;
  float acc = 0.f;
#pragma unroll 16
  for (int i = 0; i < 64; ++i) {
    float4 av = a4[i], wv = w4[i];
    acc += av.x * wv.x + av.y * wv.y + av.z * wv.z + av.w * wv.w;
  }
  return acc;
}

// In-place LayerNorm of a single 256-float LDS row; 256 threads.
DEV void ln_row(float* xs, const float* __restrict__ g, const float* __restrict__ bb,
                float* red) {
  int tid = threadIdx.x, wid = tid >> 6, lane = tid & 63;
  float v = xs[tid];
  float s = wsum(v), s2 = wsum(v * v);
  if (lane == 0) { red[wid] = s; red[4 + wid] = s2; }
  __syncthreads();
  float S = red[0] + red[1] + red[2] + red[3];
  float S2 = red[4] + red[5] + red[6] + red[7];
  float m = S * (1.f / 256.f);
  float rs = rsqrtf(S2 * (1.f / 256.f) - m * m + EPS_);
  __syncthreads();
  xs[tid] = (v - m) * rs * g[tid] + bb[tid];
  __syncthreads();
}

// In-place LayerNorm of flat [8][256] LDS rows; 256 threads.
DEV void ln8(float* x8, const float* __restrict__ g, const float* __restrict__ bb,
             float* red) {
  int tid = threadIdx.x, wid = tid >> 6, lane = tid & 63;
  for (int r = wid; r < 8; r += 4) {
    float s = 0.f, s2 = 0.f;
    for (int i = lane; i < 256; i += 64) { float v = x8[r * 256 + i]; s += v; s2 += v * v; }
    s = wsum(s); s2 = wsum(s2);
    if (lane == 0) {
      float m = s * (1.f / 256.f);
      red[r] = m;
      red[8 + r] = rsqrtf(s2 * (1.f / 256.f) - m * m + EPS_);
    }
  }
  __syncthreads();
  for (int i = tid; i < 2048; i += 256) {
    int r = i >> 8, c = i & 255;
    x8[i] = (x8[i] - red[r]) * red[8 + r] * g[c] + bb[c];
  }
  __syncthreads();
}

// generic matmul stage over all 8 batch rows, (col,b)-pair partitioned.
// out[b][c] = post( [LN?](in)[b] . W[c] + bias[c] + [LN?](resid)[b][c] )
DEV void mm_stage(int blk, int tid,
                  const float* in, int K, const float* ing, const float* inb,
                  const float* __restrict__ W, const float* __restrict__ bias,
                  const float* resid, const float* rg, const float* rb,
                  float* outp, int NCOLS, int postop,
                  const float* __restrict__ bng, const float* __restrict__ bnb,
                  float* sm_in, float* sm_re, float* red) {
  for (int i = tid; i < 8 * K; i += 256) sm_in[i] = ald(in + i);
  if (resid)
    for (int i = tid; i < 2048; i += 256) sm_re[i] = ald(resid + i);
  __syncthreads();
  if (ing) ln8(sm_in, ing, inb, red);
  if (resid && rg) ln8(sm_re, rg, rb, red);
  const int ncb = NCOLS >> 6;       // cols per block
  const int pairs = ncb << 3;       // (c,b) pairs per block
  const int PT = 256 / pairs;       // threads per pair (K-split)
  const int klen = K / PT;
  int p = tid / PT, kp = tid - p * PT;
  int c = blk * ncb + (p >> 3), b = p & 7;
  const float4* a4 = (const float4*)(sm_in + b * K + kp * klen);
  const float4* w4 = (const float4*)(W + (size_t)c * K + kp * klen);
  float acc = 0.f;
#pragma unroll
  for (int i = 0; i < klen / 4; ++i) {
    float4 av = a4[i], wv = w4[i];
    acc += av.x * wv.x + av.y * wv.y + av.z * wv.z + av.w * wv.w;
  }
  for (int off = PT >> 1; off; off >>= 1) acc += __shfl_down(acc, off, 64);
  if (kp == 0) {
    float o = acc + bias[c];
    if (resid) o += sm_re[b * 256 + c];
    if (postop == 1) o = fmaxf(o, 0.f);
    else if (postop == 2) o = fmaxf(o * BNS * bng[c] + bnb[c], 0.f);
    ast(outp + b * NCOLS + c, o);
  }
}

// self-attn stage, per (b,h) block: qkv of current token + cache append + attn.
DEV void sa_stage(int blk, int tid, int t,
                  const float* xi, const float* xg, const float* xb,
                  const float* __restrict__ W, const float* __restrict__ bq,
                  float* kcl, float* vcl, float* obuf, float* S, float* red) {
  int b = blk >> 3, h = blk & 7;
  float* xs = S;            // 256
  float* qv = S + 256;      // 32
  float* kt = S + 288;      // 32
  float* vt = S + 320;      // 32
  float* sc = S + 352;      // 64
  float (*part)[32] = (float(*)[32])(S + 416);  // [8][32]
  xs[tid] = ald(xi + b * 256 + tid);
  __syncthreads();
  if (xg) ln_row(xs, xg, xb, red);
  if (tid < 96) {
    int which = tid >> 5, j = tid & 31;
    int row = which * 256 + h * 32 + j;
    float acc = dot256(xs, W + (size_t)row * 256) + bq[row];
    if (which == 0) qv[j] = acc;
    else if (which == 1) { kt[j] = acc; kcl[((b * 8 + h) * 64 + t) * 32 + j] = acc; }
    else { vt[j] = acc; vcl[((b * 8 + h) * 64 + t) * 32 + j] = acc; }
  }
  __syncthreads();
  if (tid < 64) {
    float s = -3.0e38f;
    if (tid <= t) {
      const float* kr = (tid == t) ? kt : (kcl + ((b * 8 + h) * 64 + tid) * 32);
      float a = 0.f;
#pragma unroll
      for (int i = 0; i < 32; ++i) a += qv[i] * kr[i];
      s = a * SCALE_;
    }
    float mx = wmax(s);
    float e = (tid <= t) ? expf(s - mx) : 0.f;
    float sm = wsum(e);
    sc[tid] = e / sm;
  }
  __syncthreads();
  int g = tid >> 5, lane = tid & 31;
  float a = 0.f;
  int k0 = g * 8, k1 = min(k0 + 8, t + 1);
  for (int k = k0; k < k1; ++k) {
    const float* vr = (k == t) ? vt : (vcl + ((b * 8 + h) * 64 + k) * 32);
    a += sc[k] * vr[lane];
  }
  part[g][lane] = a;
  __syncthreads();
  if (tid < 32) {
    float o = 0.f;
#pragma unroll
    for (int gg = 0; gg < 8; ++gg) o += part[gg][tid];
    ast(obuf + b * 256 + h * 32 + tid, o);
  }
}

// cross-attn stage, per (b,h) block.
DEV void ca_stage(int blk, int tid,
                  const float* r1, const float* __restrict__ g1, const float* __restrict__ b1,
                  const float* __restrict__ wq, const float* __restrict__ bqv,
                  const float* __restrict__ mk, const float* __restrict__ mvv,
                  float* obuf2, float* S, float* red) {
  int b = blk >> 3, h = blk & 7;
  float* xs = S;            // 256
  float* qc = S + 256;      // 32
  float* ps = S + 288;      // 256
  float (*part)[32] = (float(*)[32])(S + 544);  // [8][32]
  xs[tid] = ald(r1 + b * 256 + tid);
  __syncthreads();
  ln_row(xs, g1, b1, red);
  if (tid < 32) {
    int row = h * 32 + tid;
    qc[tid] = dot256(xs, wq + (size_t)row * 256) + bqv[row];
  }
  __syncthreads();
  const float* kb = mk + (size_t)(b * 8 + h) * 256 * 32;
  float a = 0.f;
  {
    const float4* kr = (const float4*)(kb + tid * 32);
    const float4* qr = (const float4*)qc;
#pragma unroll
    for (int i = 0; i < 8; ++i) {
      float4 k4 = kr[i], q4 = qr[i];
      a += k4.x * q4.x + k4.y * q4.y + k4.z * q4.z + k4.w * q4.w;
    }
  }
  float s = a * SCALE_;
  int wid = tid >> 6, lane = tid & 63;
  float mx = wmax(s);
  if (lane == 0) red[wid] = mx;
  __syncthreads();
  mx = fmaxf(fmaxf(red[0], red[1]), fmaxf(red[2], red[3]));
  float e = expf(s - mx);
  float smv = wsum(e);
  if (lane == 0) red[4 + wid] = smv;
  __syncthreads();
  smv = red[4] + red[5] + red[6] + red[7];
  ps[tid] = e / smv;
  __syncthreads();
  int g = tid >> 5, lane2 = tid & 31;
  const float* vb = mvv + (size_t)(b * 8 + h) * 256 * 32;
  float acc = 0.f;
  for (int s2 = g * 32; s2 < g * 32 + 32; ++s2) acc += ps[s2] * vb[s2 * 32 + lane2];
  part[g][lane2] = acc;
  __syncthreads();
  if (tid < 32) {
    float o = 0.f;
#pragma unroll
    for (int gg = 0; gg < 8; ++gg) o += part[gg][tid];
    ast(obuf2 + b * 256 + h * 32 + tid, o);
  }
}

// head tail, per-b block (blk<8): logits + output write + next-step embedding.
DEV void head_stage(int blk, int tid, int t,
                    const float* ybuf,
                    const float* __restrict__ opw2, const float* __restrict__ opb2,
                    const float* __restrict__ embw, const float* __restrict__ embb,
                    const float* __restrict__ pe,
                    float* outp, float* x0, float* S) {
  int b = blk;
  float* ys = S;            // 256
  float* lg = S + 256;      // 128
  ys[tid] = ald(ybuf + b * 256 + tid);
  __syncthreads();
  if (tid < 128) {
    float v = dot256(ys, opw2 + (size_t)tid * 256) + opb2[tid];
    lg[tid] = v;
    outp[(b * 64 + t) * 128 + tid] = v;
  }
  __syncthreads();
  if (t < 63) {
    float acc = embb[tid];
    const float4* er = (const float4*)(embw + (size_t)tid * 128);
    const float4* lr = (const float4*)lg;
#pragma unroll 8
    for (int i = 0; i < 32; ++i) {
      float4 e = er[i], l = lr[i];
      acc += e.x * l.x + e.y * l.y + e.z * l.z + e.w * l.w;
    }
    ast(x0 + b * 256 + tid, acc + pe[(t + 1) * 256 + tid]);
  }
}

// ---------------------------------------------------------------------------

__global__ void __launch_bounds__(256) k_decode(
    const float* __restrict__ enc, const float* __restrict__ emb_w,
    const float* __restrict__ emb_b,
    const float* __restrict__ sa_wqkv, const float* __restrict__ sa_bqkv,
    const float* __restrict__ sa_wo, const float* __restrict__ sa_bo,
    const float* __restrict__ ca_wqkv, const float* __restrict__ ca_bqkv,
    const float* __restrict__ ca_wo, const float* __restrict__ ca_bo,
    const float* __restrict__ ln1_g, const float* __restrict__ ln1_b,
    const float* __restrict__ ln2_g, const float* __restrict__ ln2_b,
    const float* __restrict__ ffn_w1, const float* __restrict__ ffn_b1,
    const float* __restrict__ ffn_w2, const float* __restrict__ ffn_b2,
    const float* __restrict__ ln3_g, const float* __restrict__ ln3_b,
    const float* __restrict__ op_w1, const float* __restrict__ op_b1,
    const float* __restrict__ bn_g, const float* __restrict__ bn_b,
    const float* __restrict__ op_w2, const float* __restrict__ op_b2,
    int* bar, float* pe, float* mk, float* mv, float* kc, float* vc,
    float* x0, float* r1, float* r2, float* r3, float* obuf, float* obuf2,
    float* hbuf, float* ybuf, float* outp) {
  __shared__ __align__(16) float sm_in[8 * 1024];   // 32 KB
  __shared__ __align__(16) float sm_re[8 * 256];    // 8 KB
  __shared__ float sm_red[64];

  const int blk = blockIdx.x, tid = threadIdx.x;
  int mybar = 0;

  // ---- prologue: pe table, cross-attn mem K/V, x0 init ----
  {
    // pe[t=blk][d=tid]
    int d = tid, i2 = d & ~1;
    float div = __expf((float)i2 * (-9.210340371976184f / 256.f));
    float aarg = (float)blk * div;
    pe[blk * 256 + d] = (d & 1) ? __cosf(aarg) : __sinf(aarg);
    // exact values matter less than consistency; use precise versions:
    pe[blk * 256 + d] = (d & 1) ? cosf(aarg) : sinf(aarg);

    for (int vb = blk; vb < 256; vb += NBLK) {
      int l = vb >> 7, b = (vb >> 4) & 7, s0 = (vb & 15) * 16;
      const float* Wl = ca_wqkv + (size_t)l * 768 * 256;
      const float* bbv = ca_bqkv + l * 768;
      for (int i = tid; i < 4096; i += 256)
        sm_in[i] = enc[(size_t)(b * 256 + s0 + (i >> 8)) * 256 + (i & 255)];
      __syncthreads();
      for (int half = 0; half < 2; ++half) {
        const float4* wr = (const float4*)(Wl + (size_t)(256 + half * 256 + tid) * 256);
        float acc[16];
#pragma unroll
        for (int s = 0; s < 16; ++s) acc[s] = 0.f;
        for (int i = 0; i < 64; ++i) {
          float4 w = wr[i];
#pragma unroll
          for (int s = 0; s < 16; ++s) {
            float4 av = ((const float4*)(sm_in + s * 256))[i];
            acc[s] += av.x * w.x + av.y * w.y + av.z * w.z + av.w * w.w;
          }
        }
        float bias = bbv[256 + half * 256 + tid];
        float* dst = half ? mv : mk;
        int hh = tid >> 5, hd = tid & 31;
        for (int s = 0; s < 16; ++s)
          dst[((size_t)((l * 8 + b) * 8 + hh) * 256 + (s0 + s)) * 32 + hd] = acc[s] + bias;
      }
      __syncthreads();
    }
    // x0 row for t=0: buf row is zeros -> x0 = emb_b + pe[0];  pe[0,d] = (d odd ? 1 : 0)
    if (blk < 8) ast(x0 + blk * 256 + tid, emb_b[tid] + ((tid & 1) ? 1.f : 0.f));
  }
  gbar(bar, blk, tid, mybar, true);  // heavy fence: publish pe/mk/mv (normal stores)

  const size_t MK_L = (size_t)8 * 8 * 256 * 32;  // per-layer mem k/v stride
  const size_t KC_L = (size_t)8 * 8 * 64 * 32;   // per-layer cache stride

  // ---- 64 decode steps ----
  for (int t = 0; t < 64; ++t) {
    for (int l = 0; l < 2; ++l) {
      const float* xi = (l == 0) ? x0 : r3;            // r3 layer0 at offset 0
      const float* xg = (l == 0) ? nullptr : ln3_g;    // ln3 of layer 0
      const float* xb = (l == 0) ? nullptr : ln3_b;

      sa_stage(blk, tid, t, xi, xg, xb,
               sa_wqkv + (size_t)l * 768 * 256, sa_bqkv + l * 768,
               kc + l * KC_L, vc + l * KC_L, obuf, sm_in, sm_red);
      gbar(bar, blk, tid, mybar, false);

      mm_stage(blk, tid, obuf, 256, nullptr, nullptr,
               sa_wo + (size_t)l * 65536, sa_bo + l * 256,
               xi, xg, xb, r1, 256, 0, nullptr, nullptr, sm_in, sm_re, sm_red);
      gbar(bar, blk, tid, mybar, false);

      ca_stage(blk, tid, r1, ln1_g + l * 256, ln1_b + l * 256,
               ca_wqkv + (size_t)l * 768 * 256, ca_bqkv + l * 768,
               mk + l * MK_L, mv + l * MK_L, obuf2, sm_in, sm_red);
      gbar(bar, blk, tid, mybar, false);

      mm_stage(blk, tid, obuf2, 256, nullptr, nullptr,
               ca_wo + (size_t)l * 65536, ca_bo + l * 256,
               r1, ln1_g + l * 256, ln1_b + l * 256,
               r2, 256, 0, nullptr, nullptr, sm_in, sm_re, sm_red);
      gbar(bar, blk, tid, mybar, false);

      mm_stage(blk, tid, r2, 256, ln2_g + l * 256, ln2_b + l * 256,
               ffn_w1 + (size_t)l * 1024 * 256, ffn_b1 + l * 1024,
               nullptr, nullptr, nullptr, hbuf, 1024, 1, nullptr, nullptr,
               sm_in, sm_re, sm_red);
      gbar(bar, blk, tid, mybar, false);

      mm_stage(blk, tid, hbuf, 1024, nullptr, nullptr,
               ffn_w2 + (size_t)l * 256 * 1024, ffn_b2 + l * 256,
               r2, ln2_g + l * 256, ln2_b + l * 256,
               r3 + l * 2048, 256, 0, nullptr, nullptr, sm_in, sm_re, sm_red);
      gbar(bar, blk, tid, mybar, false);
    }
    // y' = relu(bn(LN3_l1(r3_l1) @ op_w1.T + op_b1))
    mm_stage(blk, tid, r3 + 2048, 256, ln3_g + 256, ln3_b + 256,
             op_w1, op_b1, nullptr, nullptr, nullptr,
             ybuf, 256, 2, bn_g, bn_b, sm_in, sm_re, sm_red);
    gbar(bar, blk, tid, mybar, false);

    if (blk < 8)
      head_stage(blk, tid, t, ybuf, op_w2, op_b2, emb_w, emb_b, pe, outp, x0, sm_in);
    gbar(bar, blk, tid, mybar, false);
  }
}

// ---------------------------------------------------------------------------

extern "C" void kernel_launch(void* const* d_in, const int* in_sizes, int n_in,
                              void* d_out, int out_size, void* d_ws, size_t ws_size,
                              hipStream_t stream) {
  (void)in_sizes; (void)n_in; (void)out_size; (void)ws_size;
  const float* enc     = (const float*)d_in[0];
  const float* emb_w   = (const float*)d_in[1];
  const float* emb_b   = (const float*)d_in[2];
  const float* sa_wqkv = (const float*)d_in[3];
  const float* sa_bqkv = (const float*)d_in[4];
  const float* sa_wo   = (const float*)d_in[5];
  const float* sa_bo   = (const float*)d_in[6];
  const float* ca_wqkv = (const float*)d_in[7];
  const float* ca_bqkv = (const float*)d_in[8];
  const float* ca_wo   = (const float*)d_in[9];
  const float* ca_bo   = (const float*)d_in[10];
  const float* ln1_g   = (const float*)d_in[11];
  const float* ln1_b   = (const float*)d_in[12];
  const float* ln2_g   = (const float*)d_in[13];
  const float* ln2_b   = (const float*)d_in[14];
  const float* ffn_w1  = (const float*)d_in[15];
  const float* ffn_b1  = (const float*)d_in[16];
  const float* ffn_w2  = (const float*)d_in[17];
  const float* ffn_b2  = (const float*)d_in[18];
  const float* ln3_g   = (const float*)d_in[19];
  const float* ln3_b   = (const float*)d_in[20];
  const float* op_w1   = (const float*)d_in[21];
  const float* op_b1   = (const float*)d_in[22];
  const float* bn_g    = (const float*)d_in[23];
  const float* bn_b    = (const float*)d_in[24];
  const float* op_w2   = (const float*)d_in[25];
  const float* op_b2   = (const float*)d_in[26];

  float* out = (float*)d_out;
  float* ws  = (float*)d_ws;

  // barrier region: first 128 floats (as ints). Zeroed every call.
  int* bar = (int*)ws;
  hipMemsetAsync(ws, 0, 512, stream);

  float* base = ws + 128;
  float* pe   = base;                       // 16384
  float* mk   = pe + 16384;                 // 1048576 (both layers)
  float* mv   = mk + 1048576;               // 1048576
  float* kc   = mv + 1048576;               // 262144
  float* vc   = kc + 262144;                // 262144
  float* x0   = vc + 262144;                // 2048
  float* r1   = x0 + 2048;                  // 2048
  float* r2   = r1 + 2048;                  // 2048
  float* r3   = r2 + 2048;                  // 4096 (two layers)
  float* obuf = r3 + 4096;                  // 2048
  float* obuf2= obuf + 2048;                // 2048
  float* hbuf = obuf2 + 2048;               // 8192
  float* ybuf = hbuf + 8192;                // 2048

  k_decode<<<NBLK, 256, 0, stream>>>(
      enc, emb_w, emb_b, sa_wqkv, sa_bqkv, sa_wo, sa_bo,
      ca_wqkv, ca_bqkv, ca_wo, ca_bo, ln1_g, ln1_b, ln2_g, ln2_b,
      ffn_w1, ffn_b1, ffn_w2, ffn_b2, ln3_g, ln3_b,
      op_w1, op_b1, bn_g, bn_b, op_w2, op_b2,
      bar, pe, mk, mv, kc, vc, x0, r1, r2, r3, obuf, obuf2, hbuf, ybuf, out);
}

// Round 3
// 5382.889 us; speedup vs baseline: 2.9713x; 1.6233x over previous
//
#include <hip/hip_runtime.h>
#include <math.h>

// ---------------------------------------------------------------------------
// TransformerDecoder: persistent-kernel KV-cache decode, dataflow-synced.
// B=8, S_SRC=256, T=64, D=256, H=8, HD=32, DFF=1024, NC=128, L=2. fp32.
// 64 blocks = 8 independent batch streams x 8 sub-roles (head h / col-group).
// Producer->consumer flag sync (relaxed agent atomics); projections fused
// into producers as per-head/per-group partials, reduced by consumers.
// 7 hops per decode step (was 14 global barriers).
// ---------------------------------------------------------------------------

#define EPS_ 1e-5f
#define SCALE_ 0.17677669529663687f   // 1/sqrt(32)
#define BNS 0.99999500003749969f      // 1/sqrt(1+1e-5)

#define DEV __device__ __forceinline__

DEV float ald(const float* p) {
  return __hip_atomic_load(p, __ATOMIC_RELAXED, __HIP_MEMORY_SCOPE_AGENT);
}
DEV void ast(float* p, float v) {
  __hip_atomic_store(p, v, __ATOMIC_RELAXED, __HIP_MEMORY_SCOPE_AGENT);
}
DEV int aldi(const int* p) {
  return __hip_atomic_load(p, __ATOMIC_RELAXED, __HIP_MEMORY_SCOPE_AGENT);
}
DEV void asti(int* p, int v) {
  __hip_atomic_store(p, v, __ATOMIC_RELAXED, __HIP_MEMORY_SCOPE_AGENT);
}

DEV float wsum(float v) {
#pragma unroll
  for (int o = 32; o; o >>= 1) v += __shfl_xor(v, o, 64);
  return v;
}
DEV float wmax(float v) {
#pragma unroll
  for (int o = 32; o; o >>= 1) v = fmaxf(v, __shfl_xor(v, o, 64));
  return v;
}

DEV float dot256(const float* a, const float* __restrict__ w) {
  const float4* a4 = (const float4*)a;
  const float4* w4 = (const float4*)w;
  float acc = 0.f;
#pragma unroll 16
  for (int i = 0; i < 64; ++i) {
    float4 av = a4[i], wv = w4[i];
    acc += av.x * wv.x + av.y * wv.y + av.z * wv.z + av.w * wv.w;
  }
  return acc;
}

// In-place LayerNorm of a 256-float LDS row; 256 threads. Each thread only
// touches its own element + shfl reductions, so no pre-sync needed.
DEV void ln_row(float* xs, const float* __restrict__ g, const float* __restrict__ bb,
                float* red) {
  int tid = threadIdx.x, wid = tid >> 6, lane = tid & 63;
  float v = xs[tid];
  float s = wsum(v), s2 = wsum(v * v);
  if (lane == 0) { red[wid] = s; red[4 + wid] = s2; }
  __syncthreads();
  float S = red[0] + red[1] + red[2] + red[3];
  float S2 = red[4] + red[5] + red[6] + red[7];
  float m = S * (1.f / 256.f);
  float rs = rsqrtf(S2 * (1.f / 256.f) - m * m + EPS_);
  __syncthreads();
  xs[tid] = (v - m) * rs * g[tid] + bb[tid];
  __syncthreads();
}

// wait until f[0..n-1] >= seq (first n lanes poll), then block-converge.
DEV void waitn(const int* f, int n, int seq) {
  if (threadIdx.x < n) { while (aldi(f + threadIdx.x) < seq) {} }
  __syncthreads();
}

// one-time global barrier for the prologue (publishes normal-store tables).
DEV void gbar(int* bar, int blk, int tid, int& mybar) {
  __syncthreads();
  ++mybar;
  if (blk == 0) {
    if (tid == 0) __threadfence();
    if (tid > 0 && tid < 64) { while (aldi(&bar[tid]) < mybar) {} }
    __syncthreads();
    if (tid == 0) asti(&bar[64], mybar);
    asm volatile("" ::: "memory");
  } else {
    if (tid == 0) {
      __threadfence();
      asti(&bar[blk], mybar);
      while (aldi(&bar[64]) < mybar) {}
    }
    asm volatile("" ::: "memory");
  }
  __syncthreads();
}

// ---------------------------------------------------------------------------

__global__ void __launch_bounds__(256) k_decode(
    const float* __restrict__ enc, const float* __restrict__ emb_w,
    const float* __restrict__ emb_b,
    const float* __restrict__ sa_wqkv, const float* __restrict__ sa_bqkv,
    const float* __restrict__ sa_wo, const float* __restrict__ sa_bo,
    const float* __restrict__ ca_wqkv, const float* __restrict__ ca_bqkv,
    const float* __restrict__ ca_wo, const float* __restrict__ ca_bo,
    const float* __restrict__ ln1_g, const float* __restrict__ ln1_b,
    const float* __restrict__ ln2_g, const float* __restrict__ ln2_b,
    const float* __restrict__ ffn_w1, const float* __restrict__ ffn_b1,
    const float* __restrict__ ffn_w2, const float* __restrict__ ffn_b2,
    const float* __restrict__ ln3_g, const float* __restrict__ ln3_b,
    const float* __restrict__ op_w1, const float* __restrict__ op_b1,
    const float* __restrict__ bn_g, const float* __restrict__ bn_b,
    const float* __restrict__ op_w2, const float* __restrict__ op_b2,
    int* bar, int* f1, int* f2, int* f3, int* f5,
    float* pe, float* mk, float* mvv, float* kc, float* vc,
    float* x0, float* r1red, float* r2red, float* r3red,
    float* p1, float* p2, float* p3, float* outp) {
  __shared__ __align__(16) float big[4096];   // 16 KB, reused per stage
  float* xs  = big;                        // 256
  float* rr  = big + 256;                  // 256
  float* aux = big + 512;                  // 256
  float* hh  = big + 768;                  // 128
  float* ov  = big + 896;                  // 128 (qv/kt/vt or qc/oc)
  float* sc  = big + 1024;                 // 64
  float (*part)[32] = (float(*)[32])(big + 1088);  // [8][32]
  float* red = big + 1344;                 // 16

  const int blk = blockIdx.x, tid = threadIdx.x;
  const int b = blk >> 3, sub = blk & 7;
  int mybar = 0;

  // ---- prologue: pe table, cross-attn mem K/V, x0 + f5 init ----
  {
    float div = expf((float)(tid & ~1) * (-9.210340371976184f / 256.f));
    float aarg = (float)blk * div;
    pe[blk * 256 + tid] = (tid & 1) ? cosf(aarg) : sinf(aarg);

    for (int vb = blk; vb < 256; vb += 64) {
      int l = vb >> 7, bb2 = (vb >> 4) & 7, s0 = (vb & 15) * 16;
      const float* Wl = ca_wqkv + (size_t)l * 768 * 256;
      for (int i = tid; i < 4096; i += 256)
        big[i] = enc[(size_t)(bb2 * 256 + s0 + (i >> 8)) * 256 + (i & 255)];
      __syncthreads();
      for (int half = 0; half < 2; ++half) {
        const float4* wr = (const float4*)(Wl + (size_t)(256 + half * 256 + tid) * 256);
        float acc[16];
#pragma unroll
        for (int s = 0; s < 16; ++s) acc[s] = 0.f;
        for (int i = 0; i < 64; ++i) {
          float4 w = wr[i];
#pragma unroll
          for (int s = 0; s < 16; ++s) {
            float4 av = ((const float4*)(big + s * 256))[i];
            acc[s] += av.x * w.x + av.y * w.y + av.z * w.z + av.w * w.w;
          }
        }
        float bias = ca_bqkv[l * 768 + 256 + half * 256 + tid];
        float* dst = half ? mvv : mk;
        int h2 = tid >> 5, hd = tid & 31;
        for (int s = 0; s < 16; ++s)
          dst[((size_t)((l * 8 + bb2) * 8 + h2) * 256 + (s0 + s)) * 32 + hd] = acc[s] + bias;
      }
      __syncthreads();
    }
    if (sub == 0) {
      // x0 for t=0: decoder buf is zeros -> x0 = emb_b + pe[0] (= 0/1 alternating)
      ast(x0 + b * 256 + tid, emb_b[tid] + ((tid & 1) ? 1.f : 0.f));
      __syncthreads();
      if (tid == 0) asti(f5 + b, 1);
    }
  }
  gbar(bar, blk, tid, mybar);   // publish pe/mk/mv (normal stores)

  // ---- 64 decode steps, 7 flag-hops each ----
  for (int t = 0; t < 64; ++t) {
    for (int l = 0; l < 2; ++l) {
      const int u = t * 2 + l, seq = u + 1;

      // ======== S1: self-attn + out-proj partial; role (b, h=sub) ========
      {
        const int h = sub;
        if (l == 0) {
          waitn(f5 + b, 1, t + 1);
          xs[tid] = ald(x0 + b * 256 + tid);
          __syncthreads();
        } else {
          waitn(f3 + b * 8, 8, u);  // f3 of (t, l=0) carries seq u
          rr[tid] = ald(r2red + 0 * 2048 + b * 256 + tid);
          __syncthreads();
          ln_row(rr, ln2_g, ln2_b, red);          // LN2, layer 0 params
          float s = 0.f;
#pragma unroll
          for (int cg = 0; cg < 8; ++cg) s += ald(p3 + (cg * 8 + b) * 256 + tid);
          float r3v = rr[tid] + s + ffn_b2[tid];  // r3 (pre-LN3), layer 0
          if (h == 0) ast(r3red + b * 256 + tid, r3v);
          xs[tid] = r3v;
          ln_row(xs, ln3_g, ln3_b, red);          // LN3, layer 0 params
        }
        // qkv for current token, cache append
        const float* W = sa_wqkv + (size_t)l * 768 * 256;
        const float* bq = sa_bqkv + l * 768;
        if (tid < 96) {
          int which = tid >> 5, j = tid & 31;
          int row = which * 256 + h * 32 + j;
          float acc = dot256(xs, W + (size_t)row * 256) + bq[row];
          if (which == 0) ov[j] = acc;
          else {
            float* cache = (which == 1 ? kc : vc) + (size_t)l * 131072 +
                           ((size_t)(b * 8 + h) * 64 + t) * 32 + j;
            *cache = acc;  // block-private: normal store
            if (which == 1) ov[32 + j] = acc; else ov[64 + j] = acc;
          }
        }
        __syncthreads();
        // causal scores over keys 0..t
        if (tid < 64) {
          float s = -3.0e38f;
          if (tid <= t) {
            const float* kr = (tid == t) ? (ov + 32)
                : kc + (size_t)l * 131072 + ((size_t)(b * 8 + h) * 64 + tid) * 32;
            float a = 0.f;
#pragma unroll
            for (int i = 0; i < 32; ++i) a += ov[i] * kr[i];
            s = a * SCALE_;
          }
          float mx = wmax(s);
          float e = (tid <= t) ? expf(s - mx) : 0.f;
          float sm = wsum(e);
          sc[tid] = e / sm;
        }
        __syncthreads();
        // PV
        {
          int g = tid >> 5, lane = tid & 31;
          float a = 0.f;
          int k0 = g * 8, k1 = k0 + 8 < t + 1 ? k0 + 8 : t + 1;
          for (int k = k0; k < k1; ++k) {
            const float* vr = (k == t) ? (ov + 64)
                : vc + (size_t)l * 131072 + ((size_t)(b * 8 + h) * 64 + k) * 32;
            a += sc[k] * vr[lane];
          }
          part[g][lane] = a;
        }
        __syncthreads();
        if (tid < 32) {
          float o = 0.f;
#pragma unroll
          for (int gg = 0; gg < 8; ++gg) o += part[gg][tid];
          aux[tid] = o;
        }
        __syncthreads();
        // out-proj partial: p1[h][b][c] = o_h . saWo[c, h*32..]
        {
          const float4* w4 = (const float4*)(sa_wo + (size_t)l * 65536 +
                                             (size_t)tid * 256 + h * 32);
          const float4* o4 = (const float4*)aux;
          float acc = 0.f;
#pragma unroll
          for (int i = 0; i < 8; ++i) {
            float4 w = w4[i], o = o4[i];
            acc += w.x * o.x + w.y * o.y + w.z * o.z + w.w * o.w;
          }
          ast(p1 + (h * 8 + b) * 256 + tid, acc);
        }
        __syncthreads();   // drains vmcnt -> data visible before flag
        if (tid == 0) asti(f1 + b * 8 + h, seq);
      }

      // ======== S2: reduce p1, cross-attn + proj partial; role (b, h=sub) ========
      {
        const int h = sub;
        waitn(f1 + b * 8, 8, seq);
        if (l == 0) {
          rr[tid] = ald(x0 + b * 256 + tid);
          __syncthreads();
        } else {
          rr[tid] = ald(r3red + b * 256 + tid);
          ln_row(rr, ln3_g, ln3_b, red);   // LN3, layer-0 params
        }
        float s = 0.f;
#pragma unroll
        for (int h2 = 0; h2 < 8; ++h2) s += ald(p1 + (h2 * 8 + b) * 256 + tid);
        float r1v = rr[tid] + s + sa_bo[l * 256 + tid];
        if (h == 0) ast(r1red + b * 256 + tid, r1v);
        xs[tid] = r1v;
        ln_row(xs, ln1_g + l * 256, ln1_b + l * 256, red);
        // qc for head h
        if (tid < 32) {
          int row = h * 32 + tid;
          ov[tid] = dot256(xs, ca_wqkv + (size_t)l * 768 * 256 + (size_t)row * 256)
                    + ca_bqkv[l * 768 + row];
        }
        __syncthreads();
        // scores over 256 memory positions
        const float* kb = mk + (size_t)l * 524288 + (size_t)(b * 8 + h) * 8192;
        float a = 0.f;
        {
          const float4* kr = (const float4*)(kb + tid * 32);
          const float4* qr = (const float4*)ov;
#pragma unroll
          for (int i = 0; i < 8; ++i) {
            float4 k4 = kr[i], q4 = qr[i];
            a += k4.x * q4.x + k4.y * q4.y + k4.z * q4.z + k4.w * q4.w;
          }
        }
        float sv = a * SCALE_;
        int wid = tid >> 6, lane = tid & 63;
        float mx = wmax(sv);
        if (lane == 0) red[wid] = mx;
        __syncthreads();
        mx = fmaxf(fmaxf(red[0], red[1]), fmaxf(red[2], red[3]));
        float e = expf(sv - mx);
        float sm = wsum(e);
        if (lane == 0) red[4 + wid] = sm;
        __syncthreads();
        sm = red[4] + red[5] + red[6] + red[7];
        aux[tid] = e / sm;
        __syncthreads();
        // PV
        {
          int g = tid >> 5, lane2 = tid & 31;
          const float* vb = mvv + (size_t)l * 524288 + (size_t)(b * 8 + h) * 8192;
          float acc = 0.f;
          for (int s2 = g * 32; s2 < g * 32 + 32; ++s2)
            acc += aux[s2] * vb[s2 * 32 + lane2];
          part[g][lane2] = acc;
        }
        __syncthreads();
        if (tid < 32) {
          float o = 0.f;
#pragma unroll
          for (int gg = 0; gg < 8; ++gg) o += part[gg][tid];
          ov[32 + tid] = o;
        }
        __syncthreads();
        // proj partial through ca_wo
        {
          const float4* w4 = (const float4*)(ca_wo + (size_t)l * 65536 +
                                             (size_t)tid * 256 + h * 32);
          const float4* o4 = (const float4*)(ov + 32);
          float acc = 0.f;
#pragma unroll
          for (int i = 0; i < 8; ++i) {
            float4 w = w4[i], o = o4[i];
            acc += w.x * o.x + w.y * o.y + w.z * o.z + w.w * o.w;
          }
          ast(p2 + (h * 8 + b) * 256 + tid, acc);
        }
        __syncthreads();
        if (tid == 0) asti(f2 + b * 8 + h, seq);
      }

      // ======== S3: reduce p2, FFN1 + FFN2-partial; role (b, cg=sub) ========
      {
        const int cg = sub;
        waitn(f2 + b * 8, 8, seq);
        rr[tid] = ald(r1red + b * 256 + tid);
        ln_row(rr, ln1_g + l * 256, ln1_b + l * 256, red);  // rr = LN1(r1)
        float s = 0.f;
#pragma unroll
        for (int h2 = 0; h2 < 8; ++h2) s += ald(p2 + (h2 * 8 + b) * 256 + tid);
        float r2v = rr[tid] + s + ca_bo[l * 256 + tid];
        if (cg == 0) ast(r2red + l * 2048 + b * 256 + tid, r2v);
        xs[tid] = r2v;
        ln_row(xs, ln2_g + l * 256, ln2_b + l * 256, red);  // xs = LN2(r2)
        // FFN1: 128 cols for this cg, 2-way K-split
        {
          int j = tid >> 1, kp = tid & 1, c = cg * 128 + j;
          const float4* a4 = (const float4*)(xs + kp * 128);
          const float4* w4 = (const float4*)(ffn_w1 + (size_t)l * 262144 +
                                             (size_t)c * 256 + kp * 128);
          float acc = 0.f;
#pragma unroll
          for (int i = 0; i < 32; ++i) {
            float4 av = a4[i], wv = w4[i];
            acc += av.x * wv.x + av.y * wv.y + av.z * wv.z + av.w * wv.w;
          }
          acc += __shfl_down(acc, 1, 64);
          if (kp == 0) hh[j] = fmaxf(acc + ffn_b1[l * 1024 + c], 0.f);
        }
        __syncthreads();
        // FFN2 partial over this cg's 128-wide k-slice, all 256 cols
        {
          const float4* h4 = (const float4*)hh;
          const float4* w4 = (const float4*)(ffn_w2 + (size_t)l * 262144 +
                                             (size_t)tid * 1024 + cg * 128);
          float acc = 0.f;
#pragma unroll
          for (int i = 0; i < 32; ++i) {
            float4 hv = h4[i], wv = w4[i];
            acc += hv.x * wv.x + hv.y * wv.y + hv.z * wv.z + hv.w * wv.w;
          }
          ast(p3 + l * 16384 + (cg * 8 + b) * 256 + tid, acc);
        }
        __syncthreads();
        if (tid == 0) asti(f3 + b * 8 + cg, seq);
      }
    }  // l

    // ======== S5: head (reduce p3 l=1, out proj, BN, logits, re-embed) ========
    if (sub == 0) {
      waitn(f3 + b * 8, 8, t * 2 + 2);
      rr[tid] = ald(r2red + 2048 + b * 256 + tid);
      __syncthreads();
      ln_row(rr, ln2_g + 256, ln2_b + 256, red);
      float s = 0.f;
#pragma unroll
      for (int cg = 0; cg < 8; ++cg) s += ald(p3 + 16384 + (cg * 8 + b) * 256 + tid);
      float r3v = rr[tid] + s + ffn_b2[256 + tid];
      xs[tid] = r3v;
      ln_row(xs, ln3_g + 256, ln3_b + 256, red);
      float y = dot256(xs, op_w1 + (size_t)tid * 256) + op_b1[tid];
      aux[tid] = fmaxf(y * BNS * bn_g[tid] + bn_b[tid], 0.f);
      __syncthreads();
      if (tid < 128) {
        float v = dot256(aux, op_w2 + (size_t)tid * 256) + op_b2[tid];
        hh[tid] = v;
        outp[((size_t)b * 64 + t) * 128 + tid] = v;
      }
      __syncthreads();
      if (t < 63) {
        const float4* er = (const float4*)(emb_w + (size_t)tid * 128);
        const float4* lr = (const float4*)hh;
        float acc = emb_b[tid];
#pragma unroll
        for (int i = 0; i < 32; ++i) {
          float4 e = er[i], l4 = lr[i];
          acc += e.x * l4.x + e.y * l4.y + e.z * l4.z + e.w * l4.w;
        }
        ast(x0 + b * 256 + tid, acc + pe[(t + 1) * 256 + tid]);
        __syncthreads();
        if (tid == 0) asti(f5 + b, t + 2);
      }
    }
  }  // t
}

// ---------------------------------------------------------------------------

extern "C" void kernel_launch(void* const* d_in, const int* in_sizes, int n_in,
                              void* d_out, int out_size, void* d_ws, size_t ws_size,
                              hipStream_t stream) {
  (void)in_sizes; (void)n_in; (void)out_size; (void)ws_size;
  const float* enc     = (const float*)d_in[0];
  const float* emb_w   = (const float*)d_in[1];
  const float* emb_b   = (const float*)d_in[2];
  const float* sa_wqkv = (const float*)d_in[3];
  const float* sa_bqkv = (const float*)d_in[4];
  const float* sa_wo   = (const float*)d_in[5];
  const float* sa_bo   = (const float*)d_in[6];
  const float* ca_wqkv = (const float*)d_in[7];
  const float* ca_bqkv = (const float*)d_in[8];
  const float* ca_wo   = (const float*)d_in[9];
  const float* ca_bo   = (const float*)d_in[10];
  const float* ln1_g   = (const float*)d_in[11];
  const float* ln1_b   = (const float*)d_in[12];
  const float* ln2_g   = (const float*)d_in[13];
  const float* ln2_b   = (const float*)d_in[14];
  const float* ffn_w1  = (const float*)d_in[15];
  const float* ffn_b1  = (const float*)d_in[16];
  const float* ffn_w2  = (const float*)d_in[17];
  const float* ffn_b2  = (const float*)d_in[18];
  const float* ln3_g   = (const float*)d_in[19];
  const float* ln3_b   = (const float*)d_in[20];
  const float* op_w1   = (const float*)d_in[21];
  const float* op_b1   = (const float*)d_in[22];
  const float* bn_g    = (const float*)d_in[23];
  const float* bn_b    = (const float*)d_in[24];
  const float* op_w2   = (const float*)d_in[25];
  const float* op_b2   = (const float*)d_in[26];

  float* out = (float*)d_out;

  // int region: bar[128], f1[64], f2[64], f3[64], f5[8]  (zeroed every call)
  int* ibase = (int*)d_ws;
  int* bar = ibase;
  int* f1  = ibase + 128;
  int* f2  = ibase + 192;
  int* f3  = ibase + 256;
  int* f5  = ibase + 320;
  hipMemsetAsync(d_ws, 0, 2048, stream);

  float* fb = (float*)d_ws + 512;
  float* pe    = fb;                    // 16384
  float* mk    = pe + 16384;            // 1048576 (2 layers)
  float* mvv   = mk + 1048576;          // 1048576
  float* kc    = mvv + 1048576;         // 262144 (2 layers)
  float* vc    = kc + 262144;           // 262144
  float* x0    = vc + 262144;           // 2048
  float* r1red = x0 + 2048;             // 2048
  float* r2red = r1red + 2048;          // 4096 (2 layers)
  float* r3red = r2red + 4096;          // 2048
  float* p1    = r3red + 2048;          // 16384
  float* p2    = p1 + 16384;            // 16384
  float* p3    = p2 + 16384;            // 32768 (2 layers)

  k_decode<<<64, 256, 0, stream>>>(
      enc, emb_w, emb_b, sa_wqkv, sa_bqkv, sa_wo, sa_bo,
      ca_wqkv, ca_bqkv, ca_wo, ca_bo, ln1_g, ln1_b, ln2_g, ln2_b,
      ffn_w1, ffn_b1, ffn_w2, ffn_b2, ln3_g, ln3_b,
      op_w1, op_b1, bn_g, bn_b, op_w2, op_b2,
      bar, f1, f2, f3, f5, pe, mk, mvv, kc, vc,
      x0, r1red, r2red, r3red, p1, p2, p3, out);
}